// Round 13
// baseline (9418.977 us; speedup 1.0000x reference)
//
#include <hip/hip_runtime.h>

#define N_ALL 20000
#define NPCD  5000
#define NRGB  15000
#define CPCD  32
#define CRGB  128
#define CF    160
#define NA    4096
#define SANS  32
#define NBK   64
#define K1    163
#define K1P   168
#define HD    128
#define FPK   288
#define NSOA  20480   // 1024 threads * 20 pts — sorted SoA padded length for FPS

// ---------------- prep: build xyz(20000x3), feat(20000x160), padded sa_W1(128x168) ----------------
__global__ void prep_kernel(const float* __restrict__ pcd_xyz,
                            const float* __restrict__ pcd_feat,
                            const float* __restrict__ rgb_xyz,
                            const float* __restrict__ rgb_feat,
                            const float* __restrict__ sa_W1,
                            float* __restrict__ xyz,
                            float* __restrict__ feat,
                            float* __restrict__ W1p) {
  const int TOT = N_ALL*CF + N_ALL*3 + HD*K1P;
  for (int id = blockIdx.x*blockDim.x + threadIdx.x; id < TOT; id += gridDim.x*blockDim.x) {
    if (id < N_ALL*CF) {
      int r = id / CF, c = id - r*CF;
      float v = 0.0f;
      if (r < NPCD) { if (c < CPCD) v = pcd_feat[r*CPCD + c]; }
      else          { if (c >= CPCD) v = rgb_feat[(c - CPCD)*NRGB + (r - NPCD)]; }
      feat[id] = v;
    } else if (id < N_ALL*CF + N_ALL*3) {
      int e = id - N_ALL*CF;
      xyz[e] = (e < NPCD*3) ? pcd_xyz[e] : rgb_xyz[e - NPCD*3];
    } else {
      int e = id - (N_ALL*CF + N_ALL*3);
      int o = e / K1P, c = e - o*K1P;
      W1p[e] = (c < K1) ? sa_W1[o*K1 + c] : 0.0f;
    }
  }
}

// ---------------- Morton sort (single block): spatial counting sort into SoA + orig-index table ----------------
static __device__ __forceinline__ unsigned spread4(unsigned v) {
  return (v & 1u) | ((v & 2u) << 2) | ((v & 4u) << 4) | ((v & 8u) << 6);
}
static __device__ __forceinline__ unsigned morton12(float x, float y, float z) {
  int ix = (int)(x * 16.0f); ix = ix < 0 ? 0 : (ix > 15 ? 15 : ix);
  int iy = (int)(y * 16.0f); iy = iy < 0 ? 0 : (iy > 15 ? 15 : iy);
  int iz = (int)(z * 16.0f); iz = iz < 0 ? 0 : (iz > 15 ? 15 : iz);
  return spread4((unsigned)ix) | (spread4((unsigned)iy) << 1) | (spread4((unsigned)iz) << 2);
}

__global__ void __launch_bounds__(1024) sort_kernel(const float* __restrict__ pcd_xyz,
                                                    const float* __restrict__ rgb_xyz,
                                                    float* __restrict__ xsoa,
                                                    float* __restrict__ ysoa,
                                                    float* __restrict__ zsoa,
                                                    unsigned short* __restrict__ orig16) {
  __shared__ unsigned hist[4096];
  __shared__ unsigned ssum[1024];
  const int t = threadIdx.x;
  for (int i = t; i < 4096; i += 1024) hist[i] = 0u;
  __syncthreads();
  for (int p = t; p < N_ALL; p += 1024) {
    float x, y, z;
    if (p < NPCD) { x = pcd_xyz[3*p]; y = pcd_xyz[3*p+1]; z = pcd_xyz[3*p+2]; }
    else { int q = p - NPCD; x = rgb_xyz[3*q]; y = rgb_xyz[3*q+1]; z = rgb_xyz[3*q+2]; }
    atomicAdd(&hist[morton12(x, y, z)], 1u);
  }
  __syncthreads();
  unsigned h0 = hist[4*t], h1 = hist[4*t+1], h2 = hist[4*t+2], h3 = hist[4*t+3];
  unsigned mysum = h0 + h1 + h2 + h3;
  ssum[t] = mysum;
  __syncthreads();
  for (int off = 1; off < 1024; off <<= 1) {
    unsigned add = (t >= off) ? ssum[t - off] : 0u;
    __syncthreads();
    ssum[t] += add;
    __syncthreads();
  }
  unsigned excl = ssum[t] - mysum;
  hist[4*t]   = excl;
  hist[4*t+1] = excl + h0;
  hist[4*t+2] = excl + h0 + h1;
  hist[4*t+3] = excl + h0 + h1 + h2;
  __syncthreads();
  for (int p = t; p < N_ALL; p += 1024) {
    float x, y, z;
    if (p < NPCD) { x = pcd_xyz[3*p]; y = pcd_xyz[3*p+1]; z = pcd_xyz[3*p+2]; }
    else { int q = p - NPCD; x = rgb_xyz[3*q]; y = rgb_xyz[3*q+1]; z = rgb_xyz[3*q+2]; }
    unsigned dst = atomicAdd(&hist[morton12(x, y, z)], 1u);
    xsoa[dst] = x; ysoa[dst] = y; zsoa[dst] = z; orig16[dst] = (unsigned short)p;
  }
  for (int i = N_ALL + t; i < NSOA; i += 1024) {
    xsoa[i] = 0.0f; ysoa[i] = 0.0f; zsoa[i] = 0.0f; orig16[i] = 0;
  }
}

// ---------------- FPS (block 0) + det_bq workers (blocks 1..157), fused launch ----------------
// R10 base (4531 us fps dispatch). ONE change: winner-coordinate publish through LDS with
// ZERO extra barriers, cutting the post-barrier dependent chain. Pre-barrier, each wave's
// winning thread (unique: k32 contains a unique pos, so exactly one lane matches
// sel_b = readlane(phase2-min, 63)) writes its winning X/Y/Z REGISTERS to cw[it&1][wv].
// Post-barrier, threads decode wavewin = pos/1280 (magic mul) from the funnel key and read
// cw (broadcast, conflict-free LDS) instead of 3 dependent global loads xsoa/ysoa/zsoa[pos]
// (~150-250 cy). Parity double-buffer is race-free: all reads of iter it complete before
// any thread passes barrier it+1, hence before any iter-it+2 overwrite. All-pad waves never
// write cw (idk never equals 0xFFFFFFFF) and never win globally => slot never read.
// cw values are exact register copies of xsoa => output bit-identical.
// (R11/R12 benches were infra failures at container acquisition — no timing fields, kernel
// never staged; identical kernel resubmitted a third time.)
typedef float v2f __attribute__((ext_vector_type(2)));

template <int CTRL>
static __device__ __forceinline__ unsigned dpp_min_u32(unsigned v) {
  int s = __builtin_amdgcn_update_dpp((int)v, (int)v, CTRL, 0xF, 0xF, false);
  unsigned u = (unsigned)s;
  return v < u ? v : u;
}

__global__ void __launch_bounds__(1024)
__attribute__((amdgpu_waves_per_eu(2, 4)))
fps_kernel(const float* __restrict__ xsoa,
           const float* __restrict__ ysoa,
           const float* __restrict__ zsoa,
           const unsigned short* __restrict__ orig16,
           const float* __restrict__ pcd_xyz,
           int* __restrict__ fidx,
           float* __restrict__ axyz,
           int* __restrict__ nbdet) {
  #pragma clang fp contract(off)
  const int t = threadIdx.x;
  const int lane = t & 63, wv = t >> 6;

  if (blockIdx.x > 0) {
    // ---- det_bq worker: wave per point, 2 points per wave ----
    int b = (int)blockIdx.x - 1;               // 0..156
    for (int e = 0; e < 2; e++) {
      int i = b*32 + wv*2 + e;
      if (i >= NPCD) break;
      float ax = pcd_xyz[3*i], ay = pcd_xyz[3*i+1], az = pcd_xyz[3*i+2];
      int cnt = 0, my = 0;
      for (int bb = 0; bb < NPCD; bb += 64) {
        int p = bb + lane;
        bool in = false;
        if (p < NPCD) {
          float dx = ax - pcd_xyz[3*p], dy = ay - pcd_xyz[3*p+1], dz = az - pcd_xyz[3*p+2];
          float d2 = (dx*dx + dy*dy) + dz*dz;
          in = d2 < 0.04f;
        }
        unsigned long long mask = __ballot(in);
        while (mask && cnt < NBK) {
          int bit = __builtin_ctzll(mask);
          mask &= mask - 1;
          if (cnt == lane) my = bb + bit;
          cnt++;
        }
        if (cnt >= NBK) break;
      }
      int f0 = __shfl(my, 0);
      nbdet[i*NBK + lane] = (lane < cnt) ? my : f0;
    }
    return;
  }

  // ---- FPS block ----
  __shared__ unsigned long long ls[4];
  __shared__ float cw[2][16][4];          // per-wave winner coords, parity double-buffered
  if (t < 4) ls[t] = ~0ull;
  const int base = 20 * t;                // contiguous sorted span
  v2f X[10], Y[10], Z[10], D[10];
  unsigned idk[20];                       // (orig<<15)|pos per slot (compile-time indexed)
  #pragma unroll
  for (int j = 0; j < 10; j++) {
    int p = base + 2*j;
    X[j] = *(const v2f*)(xsoa + p);
    Y[j] = *(const v2f*)(ysoa + p);
    Z[j] = *(const v2f*)(zsoa + p);
    D[j].x = (p     < N_ALL) ? 1e10f : -1.0f;   // sorted reals occupy [0,20000); pads never win
    D[j].y = (p + 1 < N_ALL) ? 1e10f : -1.0f;
    idk[2*j]   = ((unsigned)orig16[p]     << 15) | (unsigned)p;
    idk[2*j+1] = ((unsigned)orig16[p + 1] << 15) | (unsigned)(p + 1);
  }
  // per-thread bbox (exact fmin/fmax of members)
  float blx = 1e30f, bhx = -1e30f, bly = 1e30f, bhy = -1e30f, blz = 1e30f, bhz = -1e30f;
  #pragma unroll
  for (int j = 0; j < 10; j++) {
    blx = fminf(blx, fminf(X[j].x, X[j].y)); bhx = fmaxf(bhx, fmaxf(X[j].x, X[j].y));
    bly = fminf(bly, fminf(Y[j].x, Y[j].y)); bhy = fmaxf(bhy, fmaxf(Y[j].x, Y[j].y));
    blz = fminf(blz, fminf(Z[j].x, Z[j].y)); bhz = fmaxf(bhz, fmaxf(Z[j].x, Z[j].y));
  }
  float tmaxc = (base < N_ALL) ? 1e10f : -1.0f;     // cached tile max
  unsigned invd = 0xFFFFFFFFu, k32 = 0xFFFFFFFFu;   // cached key halves (pads: never win)
  float cx = pcd_xyz[0], cy = pcd_xyz[1], cz = pcd_xyz[2];   // orig point 0
  if (t == 0) { fidx[0] = 0; axyz[0] = cx; axyz[1] = cy; axyz[2] = cz; }
  __syncthreads();   // ls[] init visible before first atomics
  for (int it = 1; it < NA; ++it) {
    const int s = it & 3;
    const int par = it & 1;
    // conservative skip test: c-to-bbox squared distance vs cached tile max (bit-exact skip)
    float tdx = fmaxf(fmaxf(blx - cx, cx - bhx), 0.0f);
    float tdy = fmaxf(fmaxf(bly - cy, cy - bhy), 0.0f);
    float tdz = fmaxf(fmaxf(blz - cz, cz - bhz), 0.0f);
    float lb2 = (tdx*tdx + tdy*tdy) + tdz*tdz;
    if (lb2 * 0.99f < tmaxc) {
      // min-dist update (packed pair math, identical rounding to numpy)
      v2f cxv = {cx, cx}, cyv = {cy, cy}, czv = {cz, cz};
      float m[10];
      #pragma unroll
      for (int j = 0; j < 10; j++) {
        v2f dx = X[j] - cxv;
        v2f dy = Y[j] - cyv;
        v2f dz = Z[j] - czv;
        v2f d  = (dx*dx + dy*dy) + dz*dz;
        D[j].x = fminf(D[j].x, d.x);
        D[j].y = fminf(D[j].y, d.y);
        m[j] = fmaxf(D[j].x, D[j].y);
      }
      float m0 = fmaxf(m[0], m[1]), m1 = fmaxf(m[2], m[3]);
      float m2 = fmaxf(m[4], m[5]), m3 = fmaxf(m[6], m[7]);
      float tmax = fmaxf(fmaxf(fmaxf(m0, m1), fmaxf(m2, m3)), fmaxf(m[8], m[9]));
      tmaxc = tmax;
      invd = ~__float_as_uint(tmax);
      unsigned kk = 0xFFFFFFFFu;
      #pragma unroll
      for (int j = 0; j < 10; j++) {
        unsigned c0 = (D[j].x == tmax) ? idk[2*j]     : 0xFFFFFFFFu;
        unsigned c1 = (D[j].y == tmax) ? idk[2*j + 1] : 0xFFFFFFFFu;
        unsigned cm = c0 < c1 ? c0 : c1;
        kk = kk < cm ? kk : cm;
      }
      k32 = kk;
    }
    // wave argmin reduce on packed key: phase 1 min(~d_bits), phase 2 min(index | match)
    unsigned wi = invd;
    wi = dpp_min_u32<0x111>(wi);  // row_shr:1
    wi = dpp_min_u32<0x112>(wi);  // row_shr:2
    wi = dpp_min_u32<0x114>(wi);  // row_shr:4
    wi = dpp_min_u32<0x118>(wi);  // row_shr:8
    wi = dpp_min_u32<0x142>(wi);  // row_bcast:15
    wi = dpp_min_u32<0x143>(wi);  // row_bcast:31
    unsigned wmin = (unsigned)__builtin_amdgcn_readlane((int)wi, 63);
    unsigned sel = (invd == wmin) ? k32 : 0xFFFFFFFFu;
    sel = dpp_min_u32<0x111>(sel);
    sel = dpp_min_u32<0x112>(sel);
    sel = dpp_min_u32<0x114>(sel);
    sel = dpp_min_u32<0x118>(sel);
    sel = dpp_min_u32<0x142>(sel);
    sel = dpp_min_u32<0x143>(sel);
    unsigned sel_b = (unsigned)__builtin_amdgcn_readlane((int)sel, 63);
    // wave winner (unique lane: k32 contains a unique pos) publishes coords from registers
    if (k32 == sel_b) {
      #pragma unroll
      for (int j = 0; j < 10; j++) {
        if (idk[2*j]     == sel_b) { cw[par][wv][0] = X[j].x; cw[par][wv][1] = Y[j].x; cw[par][wv][2] = Z[j].x; }
        if (idk[2*j + 1] == sel_b) { cw[par][wv][0] = X[j].y; cw[par][wv][1] = Y[j].y; cw[par][wv][2] = Z[j].y; }
      }
    }
    if (lane == 63)
      atomicMin(&ls[s], ((unsigned long long)wmin << 32) | (unsigned long long)sel);
    if (t == 0) ls[(it + 2) & 3] = ~0ull;   // reset: 2 barriers from readers AND next writer
    __syncthreads();
    unsigned lo = (unsigned)ls[s];
    unsigned pos = lo & 32767u;
    unsigned wavewin = (pos * 52429u) >> 26;   // pos / 1280 for pos <= 20479
    cx = cw[par][wavewin][0]; cy = cw[par][wavewin][1]; cz = cw[par][wavewin][2];
    if (t == 0) {
      fidx[it] = (int)(lo >> 15);
      axyz[3*it] = cx; axyz[3*it+1] = cy; axyz[3*it+2] = cz;
    }
  }
}

// ---------------- ball query (wave per center): first K smallest indices with d2 < r2 ----------------
__global__ void sa_bq_kernel(const float* __restrict__ xyz,
                             const float* __restrict__ axyz,
                             int* __restrict__ nb) {
  #pragma clang fp contract(off)
  int wv = threadIdx.x >> 6, lane = threadIdx.x & 63;
  int a = blockIdx.x*4 + wv;
  float ax = axyz[3*a], ay = axyz[3*a+1], az = axyz[3*a+2];
  int cnt = 0, my = 0;
  for (int base = 0; base < N_ALL; base += 64) {
    int p = base + lane;
    bool in = false;
    if (p < N_ALL) {
      float dx = ax - xyz[3*p], dy = ay - xyz[3*p+1], dz = az - xyz[3*p+2];
      float d2 = (dx*dx + dy*dy) + dz*dz;
      in = d2 < 0.01f;
    }
    unsigned long long mask = __ballot(in);
    while (mask && cnt < SANS) {
      int b = __builtin_ctzll(mask);
      mask &= mask - 1;
      if (cnt == lane) my = base + b;
      cnt++;
    }
    if (cnt >= SANS) break;
  }
  int f0 = __shfl(my, 0);
  if (lane < SANS) nb[a*SANS + lane] = (lane < cnt) ? my : f0;
}

// ---------------- SA: gather g(32x163) -> 3x MLP(128) -> maxpool, one anchor per block ----------------
__global__ void __launch_bounds__(128) sa_mlp_kernel(const float* __restrict__ xyz,
                                                     const float* __restrict__ feat,
                                                     const float* __restrict__ axyz,
                                                     const int* __restrict__ nb,
                                                     const float* __restrict__ W1p,
                                                     const float* __restrict__ b1,
                                                     const float* __restrict__ W2,
                                                     const float* __restrict__ b2,
                                                     const float* __restrict__ W3,
                                                     const float* __restrict__ b3,
                                                     float* __restrict__ sa_feat) {
  __shared__ float g[SANS*K1P];     // 21504 B, reused as h2
  __shared__ float h1[SANS*HD];     // 16384 B
  __shared__ int nbs[SANS];
  int a = blockIdx.x, tid = threadIdx.x;
  if (tid < SANS) nbs[tid] = nb[a*SANS + tid];
  float ax = axyz[3*a], ay = axyz[3*a+1], az = axyz[3*a+2];
  __syncthreads();
  for (int e = tid; e < SANS*K1P; e += 128) {
    int s = e / K1P, c = e - s*K1P;
    float v = 0.0f;
    int p = nbs[s];
    if (c < 3) {
      float pc  = xyz[3*p + c];
      float acx = (c == 0) ? ax : ((c == 1) ? ay : az);
      v = (pc - acx) / 0.1f;
    } else if (c < K1) {
      v = feat[p*CF + (c - 3)];
    }
    g[e] = v;
  }
  __syncthreads();
  const int o = tid;
  float acc[SANS];
  // layer 1: K = 168 (zero padded)
  #pragma unroll
  for (int s = 0; s < SANS; s++) acc[s] = b1[o];
  for (int kc = 0; kc < 21; kc++) {
    const float4* wp = (const float4*)(W1p + o*K1P + kc*8);
    float4 w0 = wp[0], w1 = wp[1];
    #pragma unroll
    for (int s = 0; s < SANS; s++) {
      const float4* gp = (const float4*)(g + s*K1P + kc*8);
      float4 g0 = gp[0], g1 = gp[1];
      acc[s] += w0.x*g0.x + w0.y*g0.y + w0.z*g0.z + w0.w*g0.w
              + w1.x*g1.x + w1.y*g1.y + w1.z*g1.z + w1.w*g1.w;
    }
  }
  #pragma unroll
  for (int s = 0; s < SANS; s++) h1[s*HD + o] = fmaxf(acc[s], 0.0f);
  __syncthreads();
  // layer 2: K = 128, write h2 into g buffer
  #pragma unroll
  for (int s = 0; s < SANS; s++) acc[s] = b2[o];
  for (int kc = 0; kc < 16; kc++) {
    const float4* wp = (const float4*)(W2 + o*HD + kc*8);
    float4 w0 = wp[0], w1 = wp[1];
    #pragma unroll
    for (int s = 0; s < SANS; s++) {
      const float4* gp = (const float4*)(h1 + s*HD + kc*8);
      float4 g0 = gp[0], g1 = gp[1];
      acc[s] += w0.x*g0.x + w0.y*g0.y + w0.z*g0.z + w0.w*g0.w
              + w1.x*g1.x + w1.y*g1.y + w1.z*g1.z + w1.w*g1.w;
    }
  }
  float* h2 = g;
  #pragma unroll
  for (int s = 0; s < SANS; s++) h2[s*HD + o] = fmaxf(acc[s], 0.0f);
  __syncthreads();
  // layer 3 + max pool
  #pragma unroll
  for (int s = 0; s < SANS; s++) acc[s] = b3[o];
  for (int kc = 0; kc < 16; kc++) {
    const float4* wp = (const float4*)(W3 + o*HD + kc*8);
    float4 w0 = wp[0], w1 = wp[1];
    #pragma unroll
    for (int s = 0; s < SANS; s++) {
      const float4* gp = (const float4*)(h2 + s*HD + kc*8);
      float4 g0 = gp[0], g1 = gp[1];
      acc[s] += w0.x*g0.x + w0.y*g0.y + w0.z*g0.z + w0.w*g0.w
              + w1.x*g1.x + w1.y*g1.y + w1.z*g1.z + w1.w*g1.w;
    }
  }
  float m = 0.0f;
  #pragma unroll
  for (int s = 0; s < SANS; s++) m = fmaxf(m, fmaxf(acc[s], 0.0f));
  sa_feat[a*HD + o] = m;
}

// ---------------- 3-NN interp (first 5000 points only) + build F row [interp(128)|feat(160)] ----------------
#define INSERT3(v) { if ((v) < t0){ t2=t1; t1=t0; t0=(v);} \
                     else if ((v) < t1){ t2=t1; t1=(v);} \
                     else if ((v) < t2){ t2=(v);} }

__global__ void nn_interp_kernel(const float* __restrict__ xyz,
                                 const float* __restrict__ feat,
                                 const float* __restrict__ axyz,
                                 const float* __restrict__ sa_feat,
                                 float* __restrict__ F) {
  #pragma clang fp contract(off)
  int wv = threadIdx.x >> 6, lane = threadIdx.x & 63;
  int p = blockIdx.x*4 + wv;
  float px = xyz[3*p], py = xyz[3*p+1], pz = xyz[3*p+2];
  unsigned long long t0 = ~0ull, t1 = ~0ull, t2 = ~0ull;
  for (int j = 0; j < 64; j++) {
    int a = lane + (j << 6);
    float dx = px - axyz[3*a], dy = py - axyz[3*a+1], dz = pz - axyz[3*a+2];
    float d2 = (dx*dx + dy*dy) + dz*dz;
    unsigned long long pk = ((unsigned long long)__float_as_uint(d2) << 32) | (unsigned)a;
    INSERT3(pk);
  }
  #pragma unroll
  for (int off = 1; off < 64; off <<= 1) {
    unsigned long long b0 = __shfl_xor(t0, off);
    unsigned long long b1 = __shfl_xor(t1, off);
    unsigned long long b2 = __shfl_xor(t2, off);
    INSERT3(b0); INSERT3(b1); INSERT3(b2);
  }
  float d0 = __uint_as_float((unsigned)(t0 >> 32));
  float d1 = __uint_as_float((unsigned)(t1 >> 32));
  float d2v = __uint_as_float((unsigned)(t2 >> 32));
  int a0 = (int)(t0 & 0xFFFFFFFFull), a1 = (int)(t1 & 0xFFFFFFFFull), a2 = (int)(t2 & 0xFFFFFFFFull);
  float w0 = 1.0f/(d0 + 1e-8f), w1 = 1.0f/(d1 + 1e-8f), w2 = 1.0f/(d2v + 1e-8f);
  float wsum = w0 + w1 + w2;
  w0 /= wsum; w1 /= wsum; w2 /= wsum;
  const float* s0 = sa_feat + a0*HD;
  const float* s1 = sa_feat + a1*HD;
  const float* s2 = sa_feat + a2*HD;
  float* Fr = F + p*FPK;
  Fr[lane]      = w0*s0[lane]    + w1*s1[lane]    + w2*s2[lane];
  Fr[lane + 64] = w0*s0[lane+64] + w1*s1[lane+64] + w2*s2[lane+64];
  const float* fr = feat + p*CF;
  Fr[HD + lane]      = fr[lane];
  Fr[HD + lane + 64] = fr[lane + 64];
  if (lane < 32) Fr[HD + 128 + lane] = fr[128 + lane];
}

// ---------------- FP layer 1: (5000x288)x(288->128), relu ----------------
__global__ void __launch_bounds__(128) fp1_kernel(const float* __restrict__ F,
                                                  const float* __restrict__ W,
                                                  const float* __restrict__ b,
                                                  float* __restrict__ H) {
  __shared__ float A[32*FPK];
  int base = blockIdx.x*32, tid = threadIdx.x;
  for (int e = tid; e < 32*FPK; e += 128) {
    int r = e / FPK; int gr = base + r;
    A[e] = (gr < NPCD) ? F[gr*FPK + (e - r*FPK)] : 0.0f;
  }
  __syncthreads();
  const int o = tid;
  float acc[32];
  #pragma unroll
  for (int r = 0; r < 32; r++) acc[r] = b[o];
  for (int kc = 0; kc < 36; kc++) {
    const float4* wp = (const float4*)(W + o*FPK + kc*8);
    float4 w0 = wp[0], w1 = wp[1];
    #pragma unroll
    for (int r = 0; r < 32; r++) {
      const float4* ap = (const float4*)(A + r*FPK + kc*8);
      float4 a0 = ap[0], a1 = ap[1];
      acc[r] += w0.x*a0.x + w0.y*a0.y + w0.z*a0.z + w0.w*a0.w
              + w1.x*a1.x + w1.y*a1.y + w1.z*a1.z + w1.w*a1.w;
    }
  }
  #pragma unroll
  for (int r = 0; r < 32; r++) {
    int gr = base + r;
    if (gr < NPCD) H[gr*HD + o] = fmaxf(acc[r], 0.0f);
  }
}

// ---------------- FP layer 2: (5000x128)x(128->32), relu ----------------
__global__ void __launch_bounds__(256) fp2_kernel(const float* __restrict__ Hin,
                                                  const float* __restrict__ W,
                                                  const float* __restrict__ b,
                                                  float* __restrict__ fpf,
                                                  unsigned* __restrict__ gmax) {
  if (blockIdx.x == 0 && threadIdx.x == 0) *gmax = 0u;  // init for the gmax kernel that follows
  __shared__ float A[32*HD];
  int base = blockIdx.x*32, tid = threadIdx.x;
  for (int e = tid; e < 32*HD; e += 256) {
    int r = e >> 7; int gr = base + r;
    A[e] = (gr < NPCD) ? Hin[gr*HD + (e & 127)] : 0.0f;
  }
  __syncthreads();
  int o = tid & 31, rg = tid >> 5;
  float acc[4];
  #pragma unroll
  for (int j = 0; j < 4; j++) acc[j] = b[o];
  for (int kc = 0; kc < 16; kc++) {
    const float4* wp = (const float4*)(W + o*HD + kc*8);
    float4 w0 = wp[0], w1 = wp[1];
    #pragma unroll
    for (int j = 0; j < 4; j++) {
      int r = rg + (j << 3);
      const float4* ap = (const float4*)(A + r*HD + kc*8);
      float4 a0 = ap[0], a1 = ap[1];
      acc[j] += w0.x*a0.x + w0.y*a0.y + w0.z*a0.z + w0.w*a0.w
              + w1.x*a1.x + w1.y*a1.y + w1.z*a1.z + w1.w*a1.w;
    }
  }
  #pragma unroll
  for (int j = 0; j < 4; j++) {
    int gr = base + rg + (j << 3);
    if (gr < NPCD) fpf[gr*CPCD + o] = fmaxf(acc[j], 0.0f);
  }
}

// ---------------- global max of fp_feat (all >= 0) ----------------
__global__ void gmax_kernel(const float* __restrict__ fpf, unsigned* __restrict__ gmax) {
  int id = blockIdx.x*256 + threadIdx.x;
  float m = (id < NPCD*CPCD) ? fpf[id] : 0.0f;
  #pragma unroll
  for (int off = 1; off < 64; off <<= 1) m = fmaxf(m, __shfl_xor(m, off));
  if ((threadIdx.x & 63) == 0) atomicMax(gmax, __float_as_uint(m));
}

// ---------------- detection scores (wave per point) ----------------
__global__ void det_score_kernel(const float* __restrict__ fpf,
                                 const int* __restrict__ nbd,
                                 const unsigned* __restrict__ gmax,
                                 float* __restrict__ outs) {
  int wv = threadIdx.x >> 6, lane = threadIdx.x & 63;
  int i = blockIdx.x*4 + wv;
  float g = __uint_as_float(*gmax);
  float scale = 1.0f / (g + 1e-6f);
  int c = lane & 31, h = lane >> 5;
  float sum = 0.0f;
  const int* nbr = nbd + i*NBK + h*32;
  for (int k = 0; k < 32; k++) {
    int idx = nbr[k];
    sum += fpf[idx*CPCD + c];
  }
  sum += __shfl_xor(sum, 32);
  float mean = (sum * scale) * 0.015625f;   // /64 exact
  float fi = fpf[i*CPCD + c] * scale;
  float x = fi - mean;
  float lm = fmaxf(x, 0.0f) + log1pf(expf(-fabsf(x)));  // softplus = logaddexp(x,0)
  float dm = fi;
  #pragma unroll
  for (int off = 1; off < 64; off <<= 1) dm = fmaxf(dm, __shfl_xor(dm, off));
  float dw = fi / (1e-6f + dm);
  float pr = lm * dw;
  #pragma unroll
  for (int off = 1; off < 64; off <<= 1) pr = fmaxf(pr, __shfl_xor(pr, off));
  if (lane == 0) outs[i] = pr;
}

// ---------------- outputs: pcd_xyz copy + normalized vote_features ----------------
__global__ void vote_out_kernel(const float* __restrict__ pcd_xyz,
                                const float* __restrict__ fpf,
                                float* __restrict__ dout) {
  int id = blockIdx.x*256 + threadIdx.x;
  if (id < NPCD*3) dout[id] = pcd_xyz[id];
  int r = id - NPCD*3;
  if (r >= 0 && r < NPCD) {
    float ss = 0.0f;
    const float* fr = fpf + r*CPCD;
    #pragma unroll
    for (int cc = 0; cc < CPCD; cc++) ss += fr[cc]*fr[cc];
    float nrm = fmaxf(sqrtf(ss), 1e-12f);
    float* vf = dout + NPCD*3 + NPCD + r*CPCD;
    #pragma unroll
    for (int cc = 0; cc < CPCD; cc++) vf[cc] = fr[cc] / nrm;
  }
}

extern "C" void kernel_launch(void* const* d_in, const int* in_sizes, int n_in,
                              void* d_out, int out_size, void* d_ws, size_t ws_size,
                              hipStream_t stream) {
  const float* pcd_xyz      = (const float*)d_in[0];
  const float* pcd_features = (const float*)d_in[1];
  const float* rgb_xyz      = (const float*)d_in[2];
  const float* rgb_features = (const float*)d_in[3];
  const float* sa_W1 = (const float*)d_in[4];
  const float* sa_b1 = (const float*)d_in[5];
  const float* sa_W2 = (const float*)d_in[6];
  const float* sa_b2 = (const float*)d_in[7];
  const float* sa_W3 = (const float*)d_in[8];
  const float* sa_b3 = (const float*)d_in[9];
  const float* fp_W1 = (const float*)d_in[10];
  const float* fp_b1 = (const float*)d_in[11];
  const float* fp_W2 = (const float*)d_in[12];
  const float* fp_b2 = (const float*)d_in[13];
  float* out = (float*)d_out;

  float* xyz  = (float*)d_ws;            // 60000
  float* feat = xyz  + 60000;            // 3,200,000
  float* W1p  = feat + 3200000;          // 21,504
  float* axyz = W1p  + 21504;            // 12,288
  float* saf  = axyz + 12288;            // 524,288
  float* F    = saf  + 524288;           // 1,440,000
  float* Hb   = F    + 1440000;          // 640,000
  float* fpf  = Hb   + 640000;           // 160,000
  int*   fidx = (int*)(fpf + 160000);    // 4096
  int*   nbsa = fidx + 4096;             // 131,072
  int*   nbdet= nbsa + 131072;           // 320,000
  unsigned* gmaxp = (unsigned*)(nbdet + 320000);  // 1
  float* xsoa = (float*)(gmaxp + 1);     // 20480
  float* ysoa = xsoa + NSOA;             // 20480
  float* zsoa = ysoa + NSOA;             // 20480
  unsigned short* orig16 = (unsigned short*)(zsoa + NSOA);  // 20480 u16

  prep_kernel<<<2048, 256, 0, stream>>>(pcd_xyz, pcd_features, rgb_xyz, rgb_features,
                                        sa_W1, xyz, feat, W1p);
  sort_kernel<<<1, 1024, 0, stream>>>(pcd_xyz, rgb_xyz, xsoa, ysoa, zsoa, orig16);
  fps_kernel<<<158, 1024, 0, stream>>>(xsoa, ysoa, zsoa, orig16, pcd_xyz, fidx, axyz, nbdet);
  sa_bq_kernel<<<1024, 256, 0, stream>>>(xyz, axyz, nbsa);
  sa_mlp_kernel<<<4096, 128, 0, stream>>>(xyz, feat, axyz, nbsa, W1p, sa_b1,
                                          sa_W2, sa_b2, sa_W3, sa_b3, saf);
  nn_interp_kernel<<<1250, 256, 0, stream>>>(xyz, feat, axyz, saf, F);
  fp1_kernel<<<157, 128, 0, stream>>>(F, fp_W1, fp_b1, Hb);
  fp2_kernel<<<157, 256, 0, stream>>>(Hb, fp_W2, fp_b2, fpf, gmaxp);
  gmax_kernel<<<625, 256, 0, stream>>>(fpf, gmaxp);
  det_score_kernel<<<1250, 256, 0, stream>>>(fpf, nbdet, gmaxp, out + NPCD*3);
  vote_out_kernel<<<79, 256, 0, stream>>>(pcd_xyz, fpf, out);
}

// Round 14
// 5380.072 us; speedup vs baseline: 1.7507x; 1.7507x over previous
//
#include <hip/hip_runtime.h>

#define N_ALL 20000
#define NPCD  5000
#define NRGB  15000
#define CPCD  32
#define CRGB  128
#define CF    160
#define NA    4096
#define SANS  32
#define NBK   64
#define K1    163
#define K1P   168
#define HD    128
#define FPK   288
#define NSOA  20480   // 1024 threads * 20 pts — sorted SoA padded length for FPS

// ---------------- prep: build xyz(20000x3), feat(20000x160), padded sa_W1(128x168) ----------------
__global__ void prep_kernel(const float* __restrict__ pcd_xyz,
                            const float* __restrict__ pcd_feat,
                            const float* __restrict__ rgb_xyz,
                            const float* __restrict__ rgb_feat,
                            const float* __restrict__ sa_W1,
                            float* __restrict__ xyz,
                            float* __restrict__ feat,
                            float* __restrict__ W1p) {
  const int TOT = N_ALL*CF + N_ALL*3 + HD*K1P;
  for (int id = blockIdx.x*blockDim.x + threadIdx.x; id < TOT; id += gridDim.x*blockDim.x) {
    if (id < N_ALL*CF) {
      int r = id / CF, c = id - r*CF;
      float v = 0.0f;
      if (r < NPCD) { if (c < CPCD) v = pcd_feat[r*CPCD + c]; }
      else          { if (c >= CPCD) v = rgb_feat[(c - CPCD)*NRGB + (r - NPCD)]; }
      feat[id] = v;
    } else if (id < N_ALL*CF + N_ALL*3) {
      int e = id - N_ALL*CF;
      xyz[e] = (e < NPCD*3) ? pcd_xyz[e] : rgb_xyz[e - NPCD*3];
    } else {
      int e = id - (N_ALL*CF + N_ALL*3);
      int o = e / K1P, c = e - o*K1P;
      W1p[e] = (c < K1) ? sa_W1[o*K1 + c] : 0.0f;
    }
  }
}

// ---------------- Morton sort (single block): spatial counting sort into SoA + orig-index table ----------------
static __device__ __forceinline__ unsigned spread4(unsigned v) {
  return (v & 1u) | ((v & 2u) << 2) | ((v & 4u) << 4) | ((v & 8u) << 6);
}
static __device__ __forceinline__ unsigned morton12(float x, float y, float z) {
  int ix = (int)(x * 16.0f); ix = ix < 0 ? 0 : (ix > 15 ? 15 : ix);
  int iy = (int)(y * 16.0f); iy = iy < 0 ? 0 : (iy > 15 ? 15 : iy);
  int iz = (int)(z * 16.0f); iz = iz < 0 ? 0 : (iz > 15 ? 15 : iz);
  return spread4((unsigned)ix) | (spread4((unsigned)iy) << 1) | (spread4((unsigned)iz) << 2);
}

__global__ void __launch_bounds__(1024) sort_kernel(const float* __restrict__ pcd_xyz,
                                                    const float* __restrict__ rgb_xyz,
                                                    float* __restrict__ xsoa,
                                                    float* __restrict__ ysoa,
                                                    float* __restrict__ zsoa,
                                                    unsigned short* __restrict__ orig16) {
  __shared__ unsigned hist[4096];
  __shared__ unsigned ssum[1024];
  const int t = threadIdx.x;
  for (int i = t; i < 4096; i += 1024) hist[i] = 0u;
  __syncthreads();
  for (int p = t; p < N_ALL; p += 1024) {
    float x, y, z;
    if (p < NPCD) { x = pcd_xyz[3*p]; y = pcd_xyz[3*p+1]; z = pcd_xyz[3*p+2]; }
    else { int q = p - NPCD; x = rgb_xyz[3*q]; y = rgb_xyz[3*q+1]; z = rgb_xyz[3*q+2]; }
    atomicAdd(&hist[morton12(x, y, z)], 1u);
  }
  __syncthreads();
  unsigned h0 = hist[4*t], h1 = hist[4*t+1], h2 = hist[4*t+2], h3 = hist[4*t+3];
  unsigned mysum = h0 + h1 + h2 + h3;
  ssum[t] = mysum;
  __syncthreads();
  for (int off = 1; off < 1024; off <<= 1) {
    unsigned add = (t >= off) ? ssum[t - off] : 0u;
    __syncthreads();
    ssum[t] += add;
    __syncthreads();
  }
  unsigned excl = ssum[t] - mysum;
  hist[4*t]   = excl;
  hist[4*t+1] = excl + h0;
  hist[4*t+2] = excl + h0 + h1;
  hist[4*t+3] = excl + h0 + h1 + h2;
  __syncthreads();
  for (int p = t; p < N_ALL; p += 1024) {
    float x, y, z;
    if (p < NPCD) { x = pcd_xyz[3*p]; y = pcd_xyz[3*p+1]; z = pcd_xyz[3*p+2]; }
    else { int q = p - NPCD; x = rgb_xyz[3*q]; y = rgb_xyz[3*q+1]; z = rgb_xyz[3*q+2]; }
    unsigned dst = atomicAdd(&hist[morton12(x, y, z)], 1u);
    xsoa[dst] = x; ysoa[dst] = y; zsoa[dst] = z; orig16[dst] = (unsigned short)p;
  }
  for (int i = N_ALL + t; i < NSOA; i += 1024) {
    xsoa[i] = 0.0f; ysoa[i] = 0.0f; zsoa[i] = 0.0f; orig16[i] = 0;
  }
}

// ---------------- FPS (block 0) + det_bq workers (blocks 1..157), fused launch ----------------
// REVERT to R10 (verified 4531 us fps / 5393 us total). R13's winner-publish-via-LDS
// regressed +95%: (a) the "rare" publish branch has exactly 1 active lane per wave every
// iteration, so its 20-condition unrolled scan issues wave-wide in all 16 waves; (b) the
// 3 xsoa[pos] loads it replaced are L1-resident same-address broadcasts (cheap); (c) the
// extra DPP->readlane->compare lengthened the serial chain. Lesson: don't replace
// cache-hot broadcast loads with LDS publish machinery.
// Structure: Morton-sorted spans + exact bbox pruning (R7), packed-key DPP argmin reduce
// + 4-slot round-robin LDS atomicMin funnel, single barrier per iteration (R8), det_bq
// fused as worker blocks hidden under fps (R10). Output bit-identical to reference.
typedef float v2f __attribute__((ext_vector_type(2)));

template <int CTRL>
static __device__ __forceinline__ unsigned dpp_min_u32(unsigned v) {
  int s = __builtin_amdgcn_update_dpp((int)v, (int)v, CTRL, 0xF, 0xF, false);
  unsigned u = (unsigned)s;
  return v < u ? v : u;
}

__global__ void __launch_bounds__(1024)
__attribute__((amdgpu_waves_per_eu(2, 4)))
fps_kernel(const float* __restrict__ xsoa,
           const float* __restrict__ ysoa,
           const float* __restrict__ zsoa,
           const unsigned short* __restrict__ orig16,
           const float* __restrict__ pcd_xyz,
           int* __restrict__ fidx,
           float* __restrict__ axyz,
           int* __restrict__ nbdet) {
  #pragma clang fp contract(off)
  const int t = threadIdx.x;
  const int lane = t & 63, wv = t >> 6;

  if (blockIdx.x > 0) {
    // ---- det_bq worker: wave per point, 2 points per wave ----
    int b = (int)blockIdx.x - 1;               // 0..156
    for (int e = 0; e < 2; e++) {
      int i = b*32 + wv*2 + e;
      if (i >= NPCD) break;
      float ax = pcd_xyz[3*i], ay = pcd_xyz[3*i+1], az = pcd_xyz[3*i+2];
      int cnt = 0, my = 0;
      for (int bb = 0; bb < NPCD; bb += 64) {
        int p = bb + lane;
        bool in = false;
        if (p < NPCD) {
          float dx = ax - pcd_xyz[3*p], dy = ay - pcd_xyz[3*p+1], dz = az - pcd_xyz[3*p+2];
          float d2 = (dx*dx + dy*dy) + dz*dz;
          in = d2 < 0.04f;
        }
        unsigned long long mask = __ballot(in);
        while (mask && cnt < NBK) {
          int bit = __builtin_ctzll(mask);
          mask &= mask - 1;
          if (cnt == lane) my = bb + bit;
          cnt++;
        }
        if (cnt >= NBK) break;
      }
      int f0 = __shfl(my, 0);
      nbdet[i*NBK + lane] = (lane < cnt) ? my : f0;
    }
    return;
  }

  // ---- FPS block (R8 reduce) ----
  __shared__ unsigned long long ls[4];
  if (t < 4) ls[t] = ~0ull;
  const int base = 20 * t;                // contiguous sorted span
  v2f X[10], Y[10], Z[10], D[10];
  unsigned idk[20];                       // (orig<<15)|pos per slot (compile-time indexed)
  #pragma unroll
  for (int j = 0; j < 10; j++) {
    int p = base + 2*j;
    X[j] = *(const v2f*)(xsoa + p);
    Y[j] = *(const v2f*)(ysoa + p);
    Z[j] = *(const v2f*)(zsoa + p);
    D[j].x = (p     < N_ALL) ? 1e10f : -1.0f;   // sorted reals occupy [0,20000); pads never win
    D[j].y = (p + 1 < N_ALL) ? 1e10f : -1.0f;
    idk[2*j]   = ((unsigned)orig16[p]     << 15) | (unsigned)p;
    idk[2*j+1] = ((unsigned)orig16[p + 1] << 15) | (unsigned)(p + 1);
  }
  // per-thread bbox (exact fmin/fmax of members)
  float blx = 1e30f, bhx = -1e30f, bly = 1e30f, bhy = -1e30f, blz = 1e30f, bhz = -1e30f;
  #pragma unroll
  for (int j = 0; j < 10; j++) {
    blx = fminf(blx, fminf(X[j].x, X[j].y)); bhx = fmaxf(bhx, fmaxf(X[j].x, X[j].y));
    bly = fminf(bly, fminf(Y[j].x, Y[j].y)); bhy = fmaxf(bhy, fmaxf(Y[j].x, Y[j].y));
    blz = fminf(blz, fminf(Z[j].x, Z[j].y)); bhz = fmaxf(bhz, fmaxf(Z[j].x, Z[j].y));
  }
  float tmaxc = (base < N_ALL) ? 1e10f : -1.0f;     // cached tile max
  unsigned invd = 0xFFFFFFFFu, k32 = 0xFFFFFFFFu;   // cached key halves (pads: never win)
  float cx = pcd_xyz[0], cy = pcd_xyz[1], cz = pcd_xyz[2];   // orig point 0
  if (t == 0) { fidx[0] = 0; axyz[0] = cx; axyz[1] = cy; axyz[2] = cz; }
  __syncthreads();   // ls[] init visible before first atomics
  for (int it = 1; it < NA; ++it) {
    const int s = it & 3;
    // conservative skip test: c-to-bbox squared distance vs cached tile max (bit-exact skip)
    float tdx = fmaxf(fmaxf(blx - cx, cx - bhx), 0.0f);
    float tdy = fmaxf(fmaxf(bly - cy, cy - bhy), 0.0f);
    float tdz = fmaxf(fmaxf(blz - cz, cz - bhz), 0.0f);
    float lb2 = (tdx*tdx + tdy*tdy) + tdz*tdz;
    if (lb2 * 0.99f < tmaxc) {
      // min-dist update (packed pair math, identical rounding to numpy)
      v2f cxv = {cx, cx}, cyv = {cy, cy}, czv = {cz, cz};
      float m[10];
      #pragma unroll
      for (int j = 0; j < 10; j++) {
        v2f dx = X[j] - cxv;
        v2f dy = Y[j] - cyv;
        v2f dz = Z[j] - czv;
        v2f d  = (dx*dx + dy*dy) + dz*dz;
        D[j].x = fminf(D[j].x, d.x);
        D[j].y = fminf(D[j].y, d.y);
        m[j] = fmaxf(D[j].x, D[j].y);
      }
      float m0 = fmaxf(m[0], m[1]), m1 = fmaxf(m[2], m[3]);
      float m2 = fmaxf(m[4], m[5]), m3 = fmaxf(m[6], m[7]);
      float tmax = fmaxf(fmaxf(fmaxf(m0, m1), fmaxf(m2, m3)), fmaxf(m[8], m[9]));
      tmaxc = tmax;
      invd = ~__float_as_uint(tmax);
      unsigned kk = 0xFFFFFFFFu;
      #pragma unroll
      for (int j = 0; j < 10; j++) {
        unsigned c0 = (D[j].x == tmax) ? idk[2*j]     : 0xFFFFFFFFu;
        unsigned c1 = (D[j].y == tmax) ? idk[2*j + 1] : 0xFFFFFFFFu;
        unsigned cm = c0 < c1 ? c0 : c1;
        kk = kk < cm ? kk : cm;
      }
      k32 = kk;
    }
    // wave argmin reduce on packed key: phase 1 min(~d_bits), phase 2 min(index | match)
    unsigned wi = invd;
    wi = dpp_min_u32<0x111>(wi);  // row_shr:1
    wi = dpp_min_u32<0x112>(wi);  // row_shr:2
    wi = dpp_min_u32<0x114>(wi);  // row_shr:4
    wi = dpp_min_u32<0x118>(wi);  // row_shr:8
    wi = dpp_min_u32<0x142>(wi);  // row_bcast:15
    wi = dpp_min_u32<0x143>(wi);  // row_bcast:31
    unsigned wmin = (unsigned)__builtin_amdgcn_readlane((int)wi, 63);
    unsigned sel = (invd == wmin) ? k32 : 0xFFFFFFFFu;
    sel = dpp_min_u32<0x111>(sel);
    sel = dpp_min_u32<0x112>(sel);
    sel = dpp_min_u32<0x114>(sel);
    sel = dpp_min_u32<0x118>(sel);
    sel = dpp_min_u32<0x142>(sel);
    sel = dpp_min_u32<0x143>(sel);
    if (lane == 63)
      atomicMin(&ls[s], ((unsigned long long)wmin << 32) | (unsigned long long)sel);
    if (t == 0) ls[(it + 2) & 3] = ~0ull;   // reset: 2 barriers from readers AND next writer
    __syncthreads();
    unsigned lo = (unsigned)ls[s];
    unsigned pos = lo & 32767u;
    cx = xsoa[pos]; cy = ysoa[pos]; cz = zsoa[pos];
    if (t == 0) {
      fidx[it] = (int)(lo >> 15);
      axyz[3*it] = cx; axyz[3*it+1] = cy; axyz[3*it+2] = cz;
    }
  }
}

// ---------------- ball query (wave per center): first K smallest indices with d2 < r2 ----------------
__global__ void sa_bq_kernel(const float* __restrict__ xyz,
                             const float* __restrict__ axyz,
                             int* __restrict__ nb) {
  #pragma clang fp contract(off)
  int wv = threadIdx.x >> 6, lane = threadIdx.x & 63;
  int a = blockIdx.x*4 + wv;
  float ax = axyz[3*a], ay = axyz[3*a+1], az = axyz[3*a+2];
  int cnt = 0, my = 0;
  for (int base = 0; base < N_ALL; base += 64) {
    int p = base + lane;
    bool in = false;
    if (p < N_ALL) {
      float dx = ax - xyz[3*p], dy = ay - xyz[3*p+1], dz = az - xyz[3*p+2];
      float d2 = (dx*dx + dy*dy) + dz*dz;
      in = d2 < 0.01f;
    }
    unsigned long long mask = __ballot(in);
    while (mask && cnt < SANS) {
      int b = __builtin_ctzll(mask);
      mask &= mask - 1;
      if (cnt == lane) my = base + b;
      cnt++;
    }
    if (cnt >= SANS) break;
  }
  int f0 = __shfl(my, 0);
  if (lane < SANS) nb[a*SANS + lane] = (lane < cnt) ? my : f0;
}

// ---------------- SA: gather g(32x163) -> 3x MLP(128) -> maxpool, one anchor per block ----------------
__global__ void __launch_bounds__(128) sa_mlp_kernel(const float* __restrict__ xyz,
                                                     const float* __restrict__ feat,
                                                     const float* __restrict__ axyz,
                                                     const int* __restrict__ nb,
                                                     const float* __restrict__ W1p,
                                                     const float* __restrict__ b1,
                                                     const float* __restrict__ W2,
                                                     const float* __restrict__ b2,
                                                     const float* __restrict__ W3,
                                                     const float* __restrict__ b3,
                                                     float* __restrict__ sa_feat) {
  __shared__ float g[SANS*K1P];     // 21504 B, reused as h2
  __shared__ float h1[SANS*HD];     // 16384 B
  __shared__ int nbs[SANS];
  int a = blockIdx.x, tid = threadIdx.x;
  if (tid < SANS) nbs[tid] = nb[a*SANS + tid];
  float ax = axyz[3*a], ay = axyz[3*a+1], az = axyz[3*a+2];
  __syncthreads();
  for (int e = tid; e < SANS*K1P; e += 128) {
    int s = e / K1P, c = e - s*K1P;
    float v = 0.0f;
    int p = nbs[s];
    if (c < 3) {
      float pc  = xyz[3*p + c];
      float acx = (c == 0) ? ax : ((c == 1) ? ay : az);
      v = (pc - acx) / 0.1f;
    } else if (c < K1) {
      v = feat[p*CF + (c - 3)];
    }
    g[e] = v;
  }
  __syncthreads();
  const int o = tid;
  float acc[SANS];
  // layer 1: K = 168 (zero padded)
  #pragma unroll
  for (int s = 0; s < SANS; s++) acc[s] = b1[o];
  for (int kc = 0; kc < 21; kc++) {
    const float4* wp = (const float4*)(W1p + o*K1P + kc*8);
    float4 w0 = wp[0], w1 = wp[1];
    #pragma unroll
    for (int s = 0; s < SANS; s++) {
      const float4* gp = (const float4*)(g + s*K1P + kc*8);
      float4 g0 = gp[0], g1 = gp[1];
      acc[s] += w0.x*g0.x + w0.y*g0.y + w0.z*g0.z + w0.w*g0.w
              + w1.x*g1.x + w1.y*g1.y + w1.z*g1.z + w1.w*g1.w;
    }
  }
  #pragma unroll
  for (int s = 0; s < SANS; s++) h1[s*HD + o] = fmaxf(acc[s], 0.0f);
  __syncthreads();
  // layer 2: K = 128, write h2 into g buffer
  #pragma unroll
  for (int s = 0; s < SANS; s++) acc[s] = b2[o];
  for (int kc = 0; kc < 16; kc++) {
    const float4* wp = (const float4*)(W2 + o*HD + kc*8);
    float4 w0 = wp[0], w1 = wp[1];
    #pragma unroll
    for (int s = 0; s < SANS; s++) {
      const float4* gp = (const float4*)(h1 + s*HD + kc*8);
      float4 g0 = gp[0], g1 = gp[1];
      acc[s] += w0.x*g0.x + w0.y*g0.y + w0.z*g0.z + w0.w*g0.w
              + w1.x*g1.x + w1.y*g1.y + w1.z*g1.z + w1.w*g1.w;
    }
  }
  float* h2 = g;
  #pragma unroll
  for (int s = 0; s < SANS; s++) h2[s*HD + o] = fmaxf(acc[s], 0.0f);
  __syncthreads();
  // layer 3 + max pool
  #pragma unroll
  for (int s = 0; s < SANS; s++) acc[s] = b3[o];
  for (int kc = 0; kc < 16; kc++) {
    const float4* wp = (const float4*)(W3 + o*HD + kc*8);
    float4 w0 = wp[0], w1 = wp[1];
    #pragma unroll
    for (int s = 0; s < SANS; s++) {
      const float4* gp = (const float4*)(h2 + s*HD + kc*8);
      float4 g0 = gp[0], g1 = gp[1];
      acc[s] += w0.x*g0.x + w0.y*g0.y + w0.z*g0.z + w0.w*g0.w
              + w1.x*g1.x + w1.y*g1.y + w1.z*g1.z + w1.w*g1.w;
    }
  }
  float m = 0.0f;
  #pragma unroll
  for (int s = 0; s < SANS; s++) m = fmaxf(m, fmaxf(acc[s], 0.0f));
  sa_feat[a*HD + o] = m;
}

// ---------------- 3-NN interp (first 5000 points only) + build F row [interp(128)|feat(160)] ----------------
#define INSERT3(v) { if ((v) < t0){ t2=t1; t1=t0; t0=(v);} \
                     else if ((v) < t1){ t2=t1; t1=(v);} \
                     else if ((v) < t2){ t2=(v);} }

__global__ void nn_interp_kernel(const float* __restrict__ xyz,
                                 const float* __restrict__ feat,
                                 const float* __restrict__ axyz,
                                 const float* __restrict__ sa_feat,
                                 float* __restrict__ F) {
  #pragma clang fp contract(off)
  int wv = threadIdx.x >> 6, lane = threadIdx.x & 63;
  int p = blockIdx.x*4 + wv;
  float px = xyz[3*p], py = xyz[3*p+1], pz = xyz[3*p+2];
  unsigned long long t0 = ~0ull, t1 = ~0ull, t2 = ~0ull;
  for (int j = 0; j < 64; j++) {
    int a = lane + (j << 6);
    float dx = px - axyz[3*a], dy = py - axyz[3*a+1], dz = pz - axyz[3*a+2];
    float d2 = (dx*dx + dy*dy) + dz*dz;
    unsigned long long pk = ((unsigned long long)__float_as_uint(d2) << 32) | (unsigned)a;
    INSERT3(pk);
  }
  #pragma unroll
  for (int off = 1; off < 64; off <<= 1) {
    unsigned long long b0 = __shfl_xor(t0, off);
    unsigned long long b1 = __shfl_xor(t1, off);
    unsigned long long b2 = __shfl_xor(t2, off);
    INSERT3(b0); INSERT3(b1); INSERT3(b2);
  }
  float d0 = __uint_as_float((unsigned)(t0 >> 32));
  float d1 = __uint_as_float((unsigned)(t1 >> 32));
  float d2v = __uint_as_float((unsigned)(t2 >> 32));
  int a0 = (int)(t0 & 0xFFFFFFFFull), a1 = (int)(t1 & 0xFFFFFFFFull), a2 = (int)(t2 & 0xFFFFFFFFull);
  float w0 = 1.0f/(d0 + 1e-8f), w1 = 1.0f/(d1 + 1e-8f), w2 = 1.0f/(d2v + 1e-8f);
  float wsum = w0 + w1 + w2;
  w0 /= wsum; w1 /= wsum; w2 /= wsum;
  const float* s0 = sa_feat + a0*HD;
  const float* s1 = sa_feat + a1*HD;
  const float* s2 = sa_feat + a2*HD;
  float* Fr = F + p*FPK;
  Fr[lane]      = w0*s0[lane]    + w1*s1[lane]    + w2*s2[lane];
  Fr[lane + 64] = w0*s0[lane+64] + w1*s1[lane+64] + w2*s2[lane+64];
  const float* fr = feat + p*CF;
  Fr[HD + lane]      = fr[lane];
  Fr[HD + lane + 64] = fr[lane + 64];
  if (lane < 32) Fr[HD + 128 + lane] = fr[128 + lane];
}

// ---------------- FP layer 1: (5000x288)x(288->128), relu ----------------
__global__ void __launch_bounds__(128) fp1_kernel(const float* __restrict__ F,
                                                  const float* __restrict__ W,
                                                  const float* __restrict__ b,
                                                  float* __restrict__ H) {
  __shared__ float A[32*FPK];
  int base = blockIdx.x*32, tid = threadIdx.x;
  for (int e = tid; e < 32*FPK; e += 128) {
    int r = e / FPK; int gr = base + r;
    A[e] = (gr < NPCD) ? F[gr*FPK + (e - r*FPK)] : 0.0f;
  }
  __syncthreads();
  const int o = tid;
  float acc[32];
  #pragma unroll
  for (int r = 0; r < 32; r++) acc[r] = b[o];
  for (int kc = 0; kc < 36; kc++) {
    const float4* wp = (const float4*)(W + o*FPK + kc*8);
    float4 w0 = wp[0], w1 = wp[1];
    #pragma unroll
    for (int r = 0; r < 32; r++) {
      const float4* ap = (const float4*)(A + r*FPK + kc*8);
      float4 a0 = ap[0], a1 = ap[1];
      acc[r] += w0.x*a0.x + w0.y*a0.y + w0.z*a0.z + w0.w*a0.w
              + w1.x*a1.x + w1.y*a1.y + w1.z*a1.z + w1.w*a1.w;
    }
  }
  #pragma unroll
  for (int r = 0; r < 32; r++) {
    int gr = base + r;
    if (gr < NPCD) H[gr*HD + o] = fmaxf(acc[r], 0.0f);
  }
}

// ---------------- FP layer 2: (5000x128)x(128->32), relu ----------------
__global__ void __launch_bounds__(256) fp2_kernel(const float* __restrict__ Hin,
                                                  const float* __restrict__ W,
                                                  const float* __restrict__ b,
                                                  float* __restrict__ fpf,
                                                  unsigned* __restrict__ gmax) {
  if (blockIdx.x == 0 && threadIdx.x == 0) *gmax = 0u;  // init for the gmax kernel that follows
  __shared__ float A[32*HD];
  int base = blockIdx.x*32, tid = threadIdx.x;
  for (int e = tid; e < 32*HD; e += 256) {
    int r = e >> 7; int gr = base + r;
    A[e] = (gr < NPCD) ? Hin[gr*HD + (e & 127)] : 0.0f;
  }
  __syncthreads();
  int o = tid & 31, rg = tid >> 5;
  float acc[4];
  #pragma unroll
  for (int j = 0; j < 4; j++) acc[j] = b[o];
  for (int kc = 0; kc < 16; kc++) {
    const float4* wp = (const float4*)(W + o*HD + kc*8);
    float4 w0 = wp[0], w1 = wp[1];
    #pragma unroll
    for (int j = 0; j < 4; j++) {
      int r = rg + (j << 3);
      const float4* ap = (const float4*)(A + r*HD + kc*8);
      float4 a0 = ap[0], a1 = ap[1];
      acc[j] += w0.x*a0.x + w0.y*a0.y + w0.z*a0.z + w0.w*a0.w
              + w1.x*a1.x + w1.y*a1.y + w1.z*a1.z + w1.w*a1.w;
    }
  }
  #pragma unroll
  for (int j = 0; j < 4; j++) {
    int gr = base + rg + (j << 3);
    if (gr < NPCD) fpf[gr*CPCD + o] = fmaxf(acc[j], 0.0f);
  }
}

// ---------------- global max of fp_feat (all >= 0) ----------------
__global__ void gmax_kernel(const float* __restrict__ fpf, unsigned* __restrict__ gmax) {
  int id = blockIdx.x*256 + threadIdx.x;
  float m = (id < NPCD*CPCD) ? fpf[id] : 0.0f;
  #pragma unroll
  for (int off = 1; off < 64; off <<= 1) m = fmaxf(m, __shfl_xor(m, off));
  if ((threadIdx.x & 63) == 0) atomicMax(gmax, __float_as_uint(m));
}

// ---------------- detection scores (wave per point) ----------------
__global__ void det_score_kernel(const float* __restrict__ fpf,
                                 const int* __restrict__ nbd,
                                 const unsigned* __restrict__ gmax,
                                 float* __restrict__ outs) {
  int wv = threadIdx.x >> 6, lane = threadIdx.x & 63;
  int i = blockIdx.x*4 + wv;
  float g = __uint_as_float(*gmax);
  float scale = 1.0f / (g + 1e-6f);
  int c = lane & 31, h = lane >> 5;
  float sum = 0.0f;
  const int* nbr = nbd + i*NBK + h*32;
  for (int k = 0; k < 32; k++) {
    int idx = nbr[k];
    sum += fpf[idx*CPCD + c];
  }
  sum += __shfl_xor(sum, 32);
  float mean = (sum * scale) * 0.015625f;   // /64 exact
  float fi = fpf[i*CPCD + c] * scale;
  float x = fi - mean;
  float lm = fmaxf(x, 0.0f) + log1pf(expf(-fabsf(x)));  // softplus = logaddexp(x,0)
  float dm = fi;
  #pragma unroll
  for (int off = 1; off < 64; off <<= 1) dm = fmaxf(dm, __shfl_xor(dm, off));
  float dw = fi / (1e-6f + dm);
  float pr = lm * dw;
  #pragma unroll
  for (int off = 1; off < 64; off <<= 1) pr = fmaxf(pr, __shfl_xor(pr, off));
  if (lane == 0) outs[i] = pr;
}

// ---------------- outputs: pcd_xyz copy + normalized vote_features ----------------
__global__ void vote_out_kernel(const float* __restrict__ pcd_xyz,
                                const float* __restrict__ fpf,
                                float* __restrict__ dout) {
  int id = blockIdx.x*256 + threadIdx.x;
  if (id < NPCD*3) dout[id] = pcd_xyz[id];
  int r = id - NPCD*3;
  if (r >= 0 && r < NPCD) {
    float ss = 0.0f;
    const float* fr = fpf + r*CPCD;
    #pragma unroll
    for (int cc = 0; cc < CPCD; cc++) ss += fr[cc]*fr[cc];
    float nrm = fmaxf(sqrtf(ss), 1e-12f);
    float* vf = dout + NPCD*3 + NPCD + r*CPCD;
    #pragma unroll
    for (int cc = 0; cc < CPCD; cc++) vf[cc] = fr[cc] / nrm;
  }
}

extern "C" void kernel_launch(void* const* d_in, const int* in_sizes, int n_in,
                              void* d_out, int out_size, void* d_ws, size_t ws_size,
                              hipStream_t stream) {
  const float* pcd_xyz      = (const float*)d_in[0];
  const float* pcd_features = (const float*)d_in[1];
  const float* rgb_xyz      = (const float*)d_in[2];
  const float* rgb_features = (const float*)d_in[3];
  const float* sa_W1 = (const float*)d_in[4];
  const float* sa_b1 = (const float*)d_in[5];
  const float* sa_W2 = (const float*)d_in[6];
  const float* sa_b2 = (const float*)d_in[7];
  const float* sa_W3 = (const float*)d_in[8];
  const float* sa_b3 = (const float*)d_in[9];
  const float* fp_W1 = (const float*)d_in[10];
  const float* fp_b1 = (const float*)d_in[11];
  const float* fp_W2 = (const float*)d_in[12];
  const float* fp_b2 = (const float*)d_in[13];
  float* out = (float*)d_out;

  float* xyz  = (float*)d_ws;            // 60000
  float* feat = xyz  + 60000;            // 3,200,000
  float* W1p  = feat + 3200000;          // 21,504
  float* axyz = W1p  + 21504;            // 12,288
  float* saf  = axyz + 12288;            // 524,288
  float* F    = saf  + 524288;           // 1,440,000
  float* Hb   = F    + 1440000;          // 640,000
  float* fpf  = Hb   + 640000;           // 160,000
  int*   fidx = (int*)(fpf + 160000);    // 4096
  int*   nbsa = fidx + 4096;             // 131,072
  int*   nbdet= nbsa + 131072;           // 320,000
  unsigned* gmaxp = (unsigned*)(nbdet + 320000);  // 1
  float* xsoa = (float*)(gmaxp + 1);     // 20480
  float* ysoa = xsoa + NSOA;             // 20480
  float* zsoa = ysoa + NSOA;             // 20480
  unsigned short* orig16 = (unsigned short*)(zsoa + NSOA);  // 20480 u16

  prep_kernel<<<2048, 256, 0, stream>>>(pcd_xyz, pcd_features, rgb_xyz, rgb_features,
                                        sa_W1, xyz, feat, W1p);
  sort_kernel<<<1, 1024, 0, stream>>>(pcd_xyz, rgb_xyz, xsoa, ysoa, zsoa, orig16);
  fps_kernel<<<158, 1024, 0, stream>>>(xsoa, ysoa, zsoa, orig16, pcd_xyz, fidx, axyz, nbdet);
  sa_bq_kernel<<<1024, 256, 0, stream>>>(xyz, axyz, nbsa);
  sa_mlp_kernel<<<4096, 128, 0, stream>>>(xyz, feat, axyz, nbsa, W1p, sa_b1,
                                          sa_W2, sa_b2, sa_W3, sa_b3, saf);
  nn_interp_kernel<<<1250, 256, 0, stream>>>(xyz, feat, axyz, saf, F);
  fp1_kernel<<<157, 128, 0, stream>>>(F, fp_W1, fp_b1, Hb);
  fp2_kernel<<<157, 256, 0, stream>>>(Hb, fp_W2, fp_b2, fpf, gmaxp);
  gmax_kernel<<<625, 256, 0, stream>>>(fpf, gmaxp);
  det_score_kernel<<<1250, 256, 0, stream>>>(fpf, nbdet, gmaxp, out + NPCD*3);
  vote_out_kernel<<<79, 256, 0, stream>>>(pcd_xyz, fpf, out);
}